// Round 12
// baseline (92.789 us; speedup 1.0000x reference)
//
#include <hip/hip_runtime.h>
#include <cstdint>
#include <cstddef>

#define BB 4
#define NN 16384
#define SS 4096
#define CC 64
#define NSAMP 64
// radius*radius: python double 0.04000000000000000083 -> f32 compare -> 0.04f
#define R2 0.04f

#define TRANS_BLOCKS (BB * (NN / 64))          // 1024
#define XYZW_BLOCKS  64

typedef float f32x4 __attribute__((ext_vector_type(4)));

// ---------------------------------------------------------------------------
// Kernel 1 (prep): blocks [0,1024) transpose features (B,C,N)->(B,N,C);
// blocks [1024,1088) pack xyzw[p] = (x,y,z,0) (pure data movement).
// ---------------------------------------------------------------------------
__global__ __launch_bounds__(256) void prep_kernel(const float* __restrict__ xyz,
                                                   const float* __restrict__ feat,
                                                   float* __restrict__ featT,
                                                   f32x4* __restrict__ xyzw) {
    int t = threadIdx.x;
    if (blockIdx.x < TRANS_BLOCKS) {
        __shared__ float tile[64][65];
        int blk = blockIdx.x;
        int b   = blk / (NN / 64);
        int n0  = (blk % (NN / 64)) * 64;
        int nl  = t & 63;
        int cq  = t >> 6;
#pragma unroll
        for (int p = 0; p < 16; ++p) {
            int c = cq + p * 4;
            tile[c][nl] = feat[((size_t)b * CC + c) * NN + n0 + nl];   // coalesced
        }
        __syncthreads();
#pragma unroll
        for (int p = 0; p < 16; ++p) {
            int nl2 = cq + p * 4;
            featT[((size_t)b * NN + n0 + nl2) * CC + nl] = tile[nl][nl2]; // coalesced
        }
        return;
    }
    // ---- xyzw pack: grid-stride, scalar reads (no swizzle logic) ----
    int T0     = (blockIdx.x - TRANS_BLOCKS) * 256 + t;
    int stride = XYZW_BLOCKS * 256;
    for (int p = T0; p < BB * NN; p += stride) {
        float x = xyz[(size_t)p * 3 + 0];
        float y = xyz[(size_t)p * 3 + 1];
        float z = xyz[(size_t)p * 3 + 2];
        f32x4 o = {x, y, z, 0.0f};
        xyzw[p] = o;
    }
}

// ---------------------------------------------------------------------------
// Kernel 2: fused ball-query + group (R8 structure EXACTLY, single variable
// changed: all output stores are PLAIN (L2 write-back, line-combining)
// instead of non-temporal. Probes whether NT was throttling the 281 MB
// write stream (memsets sustain 6.9 TB/s with normal stores).
// ---------------------------------------------------------------------------
__global__ __launch_bounds__(256) void fused_qg(const f32x4* __restrict__ xyzw,
                                                const float* __restrict__ nxyz,
                                                const float* __restrict__ featT,
                                                float* __restrict__ out) {
    __shared__ float sub[4][64][17];   // per-wave 64 samples x 16ch (+1 pad)
    __shared__ int   sidx[4][NSAMP];

    int t    = threadIdx.x;
    int wid  = t >> 6;
    int lane = t & 63;
    int wg   = blockIdx.x;
    // XCD swizzle: 4096 blocks (%8==0 bijective); each XCD gets a contiguous
    // half-batch -> featT slice ~4MB = one XCD L2. Identity work mapping
    // (R9 lesson: never permute when output-write adjacency is the resource).
    int qblk = (wg & 7) * (BB * SS / 8 / 4) + (wg >> 3);
    int q    = qblk * 4 + wid;
    int b    = q >> 12;
    int s    = q & (SS - 1);

    const f32x4* xp = xyzw + (size_t)b * NN;
    float qx = nxyz[((size_t)b * SS + s) * 3 + 0];
    float qy = nxyz[((size_t)b * SS + s) * 3 + 1];
    float qz = nxyz[((size_t)b * SS + s) * 3 + 2];
    // q2 = (qx*qx + qy*qy) + qz*qz -- numpy f32 sequential, no FMA
    float q2 = __fadd_rn(__fadd_rn(__fmul_rn(qx, qx), __fmul_rn(qy, qy)),
                         __fmul_rn(qz, qz));

    // ---- phase 1: ball query (wave-private, 128 pts/iter, dwordx4 loads) ----
    int cnt = 0;
    f32x4 A  = xp[lane];
    f32x4 Bv = xp[lane + 64];
    for (int base = 0; base < NN; base += 128) {
        f32x4 ca = A, cb = Bv;
        int nb = base + 128;
        if (nb < NN) {            // uniform; prefetch next 128
            A  = xp[nb + lane];
            Bv = xp[nb + 64 + lane];
        }
        // d2 = (q2 + p2) - (qp + qp), numpy-sequential f32 (R4-identical)
        float p2a = __fadd_rn(__fadd_rn(__fmul_rn(ca.x, ca.x), __fmul_rn(ca.y, ca.y)),
                              __fmul_rn(ca.z, ca.z));
        float qpa = __fadd_rn(__fadd_rn(__fmul_rn(qx, ca.x), __fmul_rn(qy, ca.y)),
                              __fmul_rn(qz, ca.z));
        float d2a = __fsub_rn(__fadd_rn(q2, p2a), __fadd_rn(qpa, qpa));
        float p2b = __fadd_rn(__fadd_rn(__fmul_rn(cb.x, cb.x), __fmul_rn(cb.y, cb.y)),
                              __fmul_rn(cb.z, cb.z));
        float qpb = __fadd_rn(__fadd_rn(__fmul_rn(qx, cb.x), __fmul_rn(qy, cb.y)),
                              __fmul_rn(qz, cb.z));
        float d2b = __fsub_rn(__fadd_rn(q2, p2b), __fadd_rn(qpb, qpb));
        bool in0 = d2a < R2;
        bool in1 = d2b < R2;
        unsigned long long m0 = __ballot(in0);
        unsigned long long m1 = __ballot(in1);
        int c0 = __popcll(m0);
        if (in0) {
            int pos = cnt + __popcll(m0 & ((1ull << lane) - 1ull));
            if (pos < NSAMP) sidx[wid][pos] = base + lane;
        }
        if (in1) {
            int pos = cnt + c0 + __popcll(m1 & ((1ull << lane) - 1ull));
            if (pos < NSAMP) sidx[wid][pos] = base + 64 + lane;
        }
        cnt += c0 + __popcll(m1);
        if (cnt >= NSAMP) break;  // uniform
    }
    // wave-synchronous LDS: drain ds ops before reading compaction buffer
    asm volatile("s_waitcnt lgkmcnt(0)" ::: "memory");
    int total = cnt < NSAMP ? cnt : NSAMP;
    int myidx = (total == 0) ? 0 : ((lane < total) ? sidx[wid][lane] : sidx[wid][0]);
    asm volatile("s_waitcnt lgkmcnt(0)" ::: "memory");
    sidx[wid][lane] = myidx;      // normalized (first-index-filled) list
    asm volatile("s_waitcnt lgkmcnt(0)" ::: "memory");

    size_t obase = ((size_t)b * 67) * SS * 64 + (size_t)s * 64;
    size_t chs   = (size_t)SS * 64;

    // ---- grouped_xyz channels 0..2 ----
    {
        const f32x4 P = xp[myidx];
        out[obase + 0 * chs + lane] = __fsub_rn(P.x, qx);
        out[obase + 1 * chs + lane] = __fsub_rn(P.y, qy);
        out[obase + 2 * chs + lane] = __fsub_rn(P.z, qz);
    }

    // ---- phase 2: features, 4 chunks of 16 channels, pipelined ----
    const float* ftb = featT + (size_t)b * NN * CC;
    int r4 = lane >> 2;       // 0..15: row sub-index for gather
    int fc = lane & 3;        // 0..3 : f32x4 within the 16-channel chunk
    int k4 = lane & 15;       // 0..15: sample/4 index for store
    int cs = lane >> 4;       // 0..3 : channel sub-index for store

    int ridx[4];
#pragma unroll
    for (int j = 0; j < 4; ++j) ridx[j] = sidx[wid][j * 16 + r4];
    asm volatile("s_waitcnt lgkmcnt(0)" ::: "memory");

    f32x4 v[4];
#pragma unroll
    for (int j = 0; j < 4; ++j)        // prologue: gather chunk 0
        v[j] = *(const f32x4*)(ftb + (size_t)ridx[j] * CC + fc * 4);

#pragma unroll
    for (int h = 0; h < 4; ++h) {
        f32x4 w[4];
        if (h < 3) {                   // prefetch next chunk's gathers
#pragma unroll
            for (int j = 0; j < 4; ++j)
                w[j] = *(const f32x4*)(ftb + (size_t)ridx[j] * CC + (h + 1) * 16 + fc * 4);
        }
        // stage current chunk into private subtile (2-way banks = free)
#pragma unroll
        for (int j = 0; j < 4; ++j) {
            int row = j * 16 + r4;
            sub[wid][row][fc * 4 + 0] = v[j].x;
            sub[wid][row][fc * 4 + 1] = v[j].y;
            sub[wid][row][fc * 4 + 2] = v[j].z;
            sub[wid][row][fc * 4 + 3] = v[j].w;
        }
        asm volatile("s_waitcnt lgkmcnt(0)" ::: "memory");  // wave-sync LDS
        // store: per instr 4 channels x 256B contiguous segments (plain)
#pragma unroll
        for (int j = 0; j < 4; ++j) {
            int cc = j * 4 + cs;              // channel within chunk
            int c  = h * 16 + cc;             // global feature channel
            f32x4 o;
            o.x = sub[wid][k4 * 4 + 0][cc];
            o.y = sub[wid][k4 * 4 + 1][cc];
            o.z = sub[wid][k4 * 4 + 2][cc];
            o.w = sub[wid][k4 * 4 + 3][cc];
            *(f32x4*)(out + obase + (size_t)(3 + c) * chs + k4 * 4) = o;
        }
        asm volatile("s_waitcnt lgkmcnt(0)" ::: "memory");  // reads done before overwrite
#pragma unroll
        for (int j = 0; j < 4; ++j) v[j] = w[j];
    }
}

// ---------------------------------------------------------------------------
// Fallback (ws too small): fused one-wave-per-query, direct (C,N) gather.
// ---------------------------------------------------------------------------
__global__ __launch_bounds__(64) void qg_fallback(const float* __restrict__ xyz,
                                                  const float* __restrict__ nxyz,
                                                  const float* __restrict__ feat,
                                                  float* __restrict__ out) {
    __shared__ int sidx[NSAMP];
    int q = blockIdx.x;
    int b = q >> 12, s = q & (SS - 1);
    int lane = threadIdx.x;
    const float* xb = xyz + (size_t)b * NN * 3;
    float qx = nxyz[((size_t)b * SS + s) * 3 + 0];
    float qy = nxyz[((size_t)b * SS + s) * 3 + 1];
    float qz = nxyz[((size_t)b * SS + s) * 3 + 2];
    float q2 = __fadd_rn(__fadd_rn(__fmul_rn(qx, qx), __fmul_rn(qy, qy)),
                         __fmul_rn(qz, qz));
    int cnt = 0;
    for (int base = 0; base < NN; base += 64) {
        float cx = xb[(size_t)(base + lane) * 3 + 0];
        float cy = xb[(size_t)(base + lane) * 3 + 1];
        float cz = xb[(size_t)(base + lane) * 3 + 2];
        float p2 = __fadd_rn(__fadd_rn(__fmul_rn(cx, cx), __fmul_rn(cy, cy)),
                             __fmul_rn(cz, cz));
        float qp = __fadd_rn(__fadd_rn(__fmul_rn(qx, cx), __fmul_rn(qy, cy)),
                             __fmul_rn(qz, cz));
        float d2 = __fsub_rn(__fadd_rn(q2, p2), __fadd_rn(qp, qp));
        bool in = d2 < R2;
        unsigned long long m = __ballot(in);
        if (in) {
            int pos = cnt + __popcll(m & ((1ull << lane) - 1ull));
            if (pos < NSAMP) sidx[pos] = base + lane;
        }
        cnt += __popcll(m);
        if (cnt >= NSAMP) break;
    }
    __syncthreads();
    int total = cnt < NSAMP ? cnt : NSAMP;
    int myidx = (total == 0) ? 0 : ((lane < total) ? sidx[lane] : sidx[0]);
    size_t obase = ((size_t)b * 67) * SS * 64 + (size_t)s * 64;
    size_t chs   = (size_t)SS * 64;
    out[obase + 0 * chs + lane] = __fsub_rn(xb[(size_t)myidx * 3 + 0], qx);
    out[obase + 1 * chs + lane] = __fsub_rn(xb[(size_t)myidx * 3 + 1], qy);
    out[obase + 2 * chs + lane] = __fsub_rn(xb[(size_t)myidx * 3 + 2], qz);
    const float* fb = feat + (size_t)b * CC * NN;
#pragma unroll 4
    for (int c = 0; c < CC; ++c)
        out[obase + (size_t)(3 + c) * chs + lane] = fb[(size_t)c * NN + myidx];
}

// ---------------------------------------------------------------------------
extern "C" void kernel_launch(void* const* d_in, const int* in_sizes, int n_in,
                              void* d_out, int out_size, void* d_ws, size_t ws_size,
                              hipStream_t stream) {
    const float* xyz  = (const float*)d_in[0];   // (B,N,3)
    const float* nxyz = (const float*)d_in[1];   // (B,S,3)
    const float* feat = (const float*)d_in[2];   // (B,C,N)
    float* out = (float*)d_out;                  // (B,67,S,64)

    size_t needT = (size_t)BB * NN * CC * sizeof(float);        // 16 MB
    size_t needW = (size_t)BB * NN * 4 * sizeof(float);         //  1 MB
    if (ws_size >= needT + needW) {
        float* featT = (float*)d_ws;
        f32x4* xyzw  = (f32x4*)((char*)d_ws + needT);
        prep_kernel<<<TRANS_BLOCKS + XYZW_BLOCKS, 256, 0, stream>>>(xyz, feat,
                                                                    featT, xyzw);
        fused_qg<<<BB * SS / 4, 256, 0, stream>>>(xyzw, nxyz, featT, out);
    } else {
        qg_fallback<<<BB * SS, 64, 0, stream>>>(xyz, nxyz, feat, out);
    }
}

// Round 13
// 82.228 us; speedup vs baseline: 1.1284x; 1.1284x over previous
//
#include <hip/hip_runtime.h>
#include <cstdint>
#include <cstddef>

#define BB 4
#define NN 16384
#define SS 4096
#define CC 64
#define NSAMP 64
// radius*radius: python double 0.04000000000000000083 -> f32 compare -> 0.04f
#define R2 0.04f

#define TRANS_BLOCKS (BB * (NN / 64))          // 1024
#define XYZW_BLOCKS  64

typedef float f32x4 __attribute__((ext_vector_type(4)));

// ---------------------------------------------------------------------------
// Kernel 1 (prep): blocks [0,1024) transpose features (B,C,N)->(B,N,C);
// blocks [1024,1088) pack xyzw[p] = (x,y,z,0) (pure data movement).
// ---------------------------------------------------------------------------
__global__ __launch_bounds__(256) void prep_kernel(const float* __restrict__ xyz,
                                                   const float* __restrict__ feat,
                                                   float* __restrict__ featT,
                                                   f32x4* __restrict__ xyzw) {
    int t = threadIdx.x;
    if (blockIdx.x < TRANS_BLOCKS) {
        __shared__ float tile[64][65];
        int blk = blockIdx.x;
        int b   = blk / (NN / 64);
        int n0  = (blk % (NN / 64)) * 64;
        int nl  = t & 63;
        int cq  = t >> 6;
#pragma unroll
        for (int p = 0; p < 16; ++p) {
            int c = cq + p * 4;
            tile[c][nl] = feat[((size_t)b * CC + c) * NN + n0 + nl];   // coalesced
        }
        __syncthreads();
#pragma unroll
        for (int p = 0; p < 16; ++p) {
            int nl2 = cq + p * 4;
            featT[((size_t)b * NN + n0 + nl2) * CC + nl] = tile[nl][nl2]; // coalesced
        }
        return;
    }
    // ---- xyzw pack: grid-stride, scalar reads (no swizzle logic) ----
    int T0     = (blockIdx.x - TRANS_BLOCKS) * 256 + t;
    int stride = XYZW_BLOCKS * 256;
    for (int p = T0; p < BB * NN; p += stride) {
        float x = xyz[(size_t)p * 3 + 0];
        float y = xyz[(size_t)p * 3 + 1];
        float z = xyz[(size_t)p * 3 + 2];
        f32x4 o = {x, y, z, 0.0f};
        xyzw[p] = o;
    }
}

// ---------------------------------------------------------------------------
// Kernel 2: fused ball-query + group. R8 structure (NT stores, [64][17]
// per-wave subtiles, R8 gather geometry, 32 waves/CU) with ONE change:
// CROSS-WAVE STORES. The block's 4 waves hold 4 adjacent queries; after a
// per-chunk __syncthreads, each store instruction writes one channel for
// all 4 queries = 64 lanes x 16B = 1KB CONTIGUOUS (4x R8's 256B segments).
// Same store-instruction count; 2 barriers per chunk (8 total).
// ---------------------------------------------------------------------------
__global__ __launch_bounds__(256) void fused_qg(const f32x4* __restrict__ xyzw,
                                                const float* __restrict__ nxyz,
                                                const float* __restrict__ featT,
                                                float* __restrict__ out) {
    __shared__ float sub[4][64][17];   // per-wave 64 samples x 16ch (+1 pad)
    __shared__ int   sidx[4][NSAMP];

    int t    = threadIdx.x;
    int wid  = t >> 6;
    int lane = t & 63;
    int wg   = blockIdx.x;
    // XCD swizzle: 4096 blocks (%8==0 bijective); each XCD gets a contiguous
    // half-batch -> featT slice ~4MB = one XCD L2. Identity work mapping
    // (R9 lesson: never permute when output-write adjacency is the resource).
    int qblk = (wg & 7) * (BB * SS / 8 / 4) + (wg >> 3);
    int q0   = qblk * 4;              // block's 4 adjacent queries (same b)
    int q    = q0 + wid;
    int b    = q >> 12;
    int s    = q & (SS - 1);

    const f32x4* xp = xyzw + (size_t)b * NN;
    float qx = nxyz[((size_t)b * SS + s) * 3 + 0];
    float qy = nxyz[((size_t)b * SS + s) * 3 + 1];
    float qz = nxyz[((size_t)b * SS + s) * 3 + 2];
    // q2 = (qx*qx + qy*qy) + qz*qz -- numpy f32 sequential, no FMA
    float q2 = __fadd_rn(__fadd_rn(__fmul_rn(qx, qx), __fmul_rn(qy, qy)),
                         __fmul_rn(qz, qz));

    // ---- phase 1: ball query (wave-private, 128 pts/iter, dwordx4 loads) ----
    int cnt = 0;
    f32x4 A  = xp[lane];
    f32x4 Bv = xp[lane + 64];
    for (int base = 0; base < NN; base += 128) {
        f32x4 ca = A, cb = Bv;
        int nb = base + 128;
        if (nb < NN) {            // uniform; prefetch next 128
            A  = xp[nb + lane];
            Bv = xp[nb + 64 + lane];
        }
        // d2 = (q2 + p2) - (qp + qp), numpy-sequential f32 (R4-identical)
        float p2a = __fadd_rn(__fadd_rn(__fmul_rn(ca.x, ca.x), __fmul_rn(ca.y, ca.y)),
                              __fmul_rn(ca.z, ca.z));
        float qpa = __fadd_rn(__fadd_rn(__fmul_rn(qx, ca.x), __fmul_rn(qy, ca.y)),
                              __fmul_rn(qz, ca.z));
        float d2a = __fsub_rn(__fadd_rn(q2, p2a), __fadd_rn(qpa, qpa));
        float p2b = __fadd_rn(__fadd_rn(__fmul_rn(cb.x, cb.x), __fmul_rn(cb.y, cb.y)),
                              __fmul_rn(cb.z, cb.z));
        float qpb = __fadd_rn(__fadd_rn(__fmul_rn(qx, cb.x), __fmul_rn(qy, cb.y)),
                              __fmul_rn(qz, cb.z));
        float d2b = __fsub_rn(__fadd_rn(q2, p2b), __fadd_rn(qpb, qpb));
        bool in0 = d2a < R2;
        bool in1 = d2b < R2;
        unsigned long long m0 = __ballot(in0);
        unsigned long long m1 = __ballot(in1);
        int c0 = __popcll(m0);
        if (in0) {
            int pos = cnt + __popcll(m0 & ((1ull << lane) - 1ull));
            if (pos < NSAMP) sidx[wid][pos] = base + lane;
        }
        if (in1) {
            int pos = cnt + c0 + __popcll(m1 & ((1ull << lane) - 1ull));
            if (pos < NSAMP) sidx[wid][pos] = base + 64 + lane;
        }
        cnt += c0 + __popcll(m1);
        if (cnt >= NSAMP) break;  // uniform
    }
    // wave-synchronous LDS: drain ds ops before reading compaction buffer
    asm volatile("s_waitcnt lgkmcnt(0)" ::: "memory");
    int total = cnt < NSAMP ? cnt : NSAMP;
    int myidx = (total == 0) ? 0 : ((lane < total) ? sidx[wid][lane] : sidx[wid][0]);
    asm volatile("s_waitcnt lgkmcnt(0)" ::: "memory");
    sidx[wid][lane] = myidx;      // normalized (first-index-filled) list
    asm volatile("s_waitcnt lgkmcnt(0)" ::: "memory");

    size_t chs     = (size_t)SS * 64;
    int    s0      = q0 & (SS - 1);
    size_t obaseBk = ((size_t)b * 67) * SS * 64 + (size_t)s0 * 64;  // block base
    size_t obase   = obaseBk + (size_t)wid * 64;                    // own query

    // ---- grouped_xyz channels 0..2 (own query, 256B NT segments) ----
    {
        const f32x4 P = xp[myidx];
        float gx = __fsub_rn(P.x, qx);
        float gy = __fsub_rn(P.y, qy);
        float gz = __fsub_rn(P.z, qz);
        __builtin_nontemporal_store(gx, out + obase + 0 * chs + lane);
        __builtin_nontemporal_store(gy, out + obase + 1 * chs + lane);
        __builtin_nontemporal_store(gz, out + obase + 2 * chs + lane);
    }

    // ---- phase 2: features, 4 chunks of 16 channels, pipelined ----
    const float* ftb = featT + (size_t)b * NN * CC;
    int r4 = lane >> 2;       // 0..15: row sub-index for gather (own query)
    int fc = lane & 3;        // 0..3 : f32x4 within the 16-channel chunk
    int qi = lane >> 4;       // 0..3 : query index for cross-wave store
    int k4 = lane & 15;       // 0..15: sample/4 index for store

    int ridx[4];
#pragma unroll
    for (int j = 0; j < 4; ++j) ridx[j] = sidx[wid][j * 16 + r4];
    asm volatile("s_waitcnt lgkmcnt(0)" ::: "memory");

    f32x4 v[4];
#pragma unroll
    for (int j = 0; j < 4; ++j)        // prologue: gather chunk 0 (own query)
        v[j] = *(const f32x4*)(ftb + (size_t)ridx[j] * CC + fc * 4);

#pragma unroll
    for (int h = 0; h < 4; ++h) {
        f32x4 w[4];
        if (h < 3) {                   // prefetch next chunk's gathers
#pragma unroll
            for (int j = 0; j < 4; ++j)
                w[j] = *(const f32x4*)(ftb + (size_t)ridx[j] * CC + (h + 1) * 16 + fc * 4);
        }
        // stage current chunk into own subtile (2-way banks = free)
#pragma unroll
        for (int j = 0; j < 4; ++j) {
            int row = j * 16 + r4;
            sub[wid][row][fc * 4 + 0] = v[j].x;
            sub[wid][row][fc * 4 + 1] = v[j].y;
            sub[wid][row][fc * 4 + 2] = v[j].z;
            sub[wid][row][fc * 4 + 3] = v[j].w;
        }
        __syncthreads();               // all 4 subtiles staged
        // CROSS-WAVE store: wave wid owns channels [h*16+wid*4, +4).
        // One instr = one channel x 4 queries x 64 samples = 1KB contiguous.
#pragma unroll
        for (int j = 0; j < 4; ++j) {
            int cc = wid * 4 + j;             // channel within chunk
            int c  = h * 16 + cc;             // global feature channel
            f32x4 o;
            o.x = sub[qi][k4 * 4 + 0][cc];
            o.y = sub[qi][k4 * 4 + 1][cc];
            o.z = sub[qi][k4 * 4 + 2][cc];
            o.w = sub[qi][k4 * 4 + 3][cc];
            __builtin_nontemporal_store(o,
                (f32x4*)(out + obaseBk + (size_t)(3 + c) * chs + (size_t)lane * 4));
        }
        __syncthreads();               // reads done before next-chunk staging
#pragma unroll
        for (int j = 0; j < 4; ++j) v[j] = w[j];
    }
}

// ---------------------------------------------------------------------------
// Fallback (ws too small): fused one-wave-per-query, direct (C,N) gather.
// ---------------------------------------------------------------------------
__global__ __launch_bounds__(64) void qg_fallback(const float* __restrict__ xyz,
                                                  const float* __restrict__ nxyz,
                                                  const float* __restrict__ feat,
                                                  float* __restrict__ out) {
    __shared__ int sidx[NSAMP];
    int q = blockIdx.x;
    int b = q >> 12, s = q & (SS - 1);
    int lane = threadIdx.x;
    const float* xb = xyz + (size_t)b * NN * 3;
    float qx = nxyz[((size_t)b * SS + s) * 3 + 0];
    float qy = nxyz[((size_t)b * SS + s) * 3 + 1];
    float qz = nxyz[((size_t)b * SS + s) * 3 + 2];
    float q2 = __fadd_rn(__fadd_rn(__fmul_rn(qx, qx), __fmul_rn(qy, qy)),
                         __fmul_rn(qz, qz));
    int cnt = 0;
    for (int base = 0; base < NN; base += 64) {
        float cx = xb[(size_t)(base + lane) * 3 + 0];
        float cy = xb[(size_t)(base + lane) * 3 + 1];
        float cz = xb[(size_t)(base + lane) * 3 + 2];
        float p2 = __fadd_rn(__fadd_rn(__fmul_rn(cx, cx), __fmul_rn(cy, cy)),
                             __fmul_rn(cz, cz));
        float qp = __fadd_rn(__fadd_rn(__fmul_rn(qx, cx), __fmul_rn(qy, cy)),
                             __fmul_rn(qz, cz));
        float d2 = __fsub_rn(__fadd_rn(q2, p2), __fadd_rn(qp, qp));
        bool in = d2 < R2;
        unsigned long long m = __ballot(in);
        if (in) {
            int pos = cnt + __popcll(m & ((1ull << lane) - 1ull));
            if (pos < NSAMP) sidx[pos] = base + lane;
        }
        cnt += __popcll(m);
        if (cnt >= NSAMP) break;
    }
    __syncthreads();
    int total = cnt < NSAMP ? cnt : NSAMP;
    int myidx = (total == 0) ? 0 : ((lane < total) ? sidx[lane] : sidx[0]);
    size_t obase = ((size_t)b * 67) * SS * 64 + (size_t)s * 64;
    size_t chs   = (size_t)SS * 64;
    out[obase + 0 * chs + lane] = __fsub_rn(xb[(size_t)myidx * 3 + 0], qx);
    out[obase + 1 * chs + lane] = __fsub_rn(xb[(size_t)myidx * 3 + 1], qy);
    out[obase + 2 * chs + lane] = __fsub_rn(xb[(size_t)myidx * 3 + 2], qz);
    const float* fb = feat + (size_t)b * CC * NN;
#pragma unroll 4
    for (int c = 0; c < CC; ++c)
        out[obase + (size_t)(3 + c) * chs + lane] = fb[(size_t)c * NN + myidx];
}

// ---------------------------------------------------------------------------
extern "C" void kernel_launch(void* const* d_in, const int* in_sizes, int n_in,
                              void* d_out, int out_size, void* d_ws, size_t ws_size,
                              hipStream_t stream) {
    const float* xyz  = (const float*)d_in[0];   // (B,N,3)
    const float* nxyz = (const float*)d_in[1];   // (B,S,3)
    const float* feat = (const float*)d_in[2];   // (B,C,N)
    float* out = (float*)d_out;                  // (B,67,S,64)

    size_t needT = (size_t)BB * NN * CC * sizeof(float);        // 16 MB
    size_t needW = (size_t)BB * NN * 4 * sizeof(float);         //  1 MB
    if (ws_size >= needT + needW) {
        float* featT = (float*)d_ws;
        f32x4* xyzw  = (f32x4*)((char*)d_ws + needT);
        prep_kernel<<<TRANS_BLOCKS + XYZW_BLOCKS, 256, 0, stream>>>(xyz, feat,
                                                                    featT, xyzw);
        fused_qg<<<BB * SS / 4, 256, 0, stream>>>(xyzw, nxyz, featT, out);
    } else {
        qg_fallback<<<BB * SS, 64, 0, stream>>>(xyz, nxyz, feat, out);
    }
}

// Round 14
// 80.404 us; speedup vs baseline: 1.1540x; 1.0227x over previous
//
#include <hip/hip_runtime.h>
#include <cstdint>
#include <cstddef>

#define BB 4
#define NN 16384
#define SS 4096
#define CC 64
#define NSAMP 64
// radius*radius: python double 0.04000000000000000083 -> f32 compare -> 0.04f
#define R2 0.04f

#define TRANS_BLOCKS (BB * (NN / 64))          // 1024
#define XYZW_BLOCKS  64

typedef float f32x4 __attribute__((ext_vector_type(4)));

// ---------------------------------------------------------------------------
// Kernel 1 (prep): blocks [0,1024) transpose features (B,C,N)->(B,N,C);
// blocks [1024,1088) pack xyzw[p] = (x,y,z,0) (pure data movement).
// ---------------------------------------------------------------------------
__global__ __launch_bounds__(256) void prep_kernel(const float* __restrict__ xyz,
                                                   const float* __restrict__ feat,
                                                   float* __restrict__ featT,
                                                   f32x4* __restrict__ xyzw) {
    int t = threadIdx.x;
    if (blockIdx.x < TRANS_BLOCKS) {
        __shared__ float tile[64][65];
        int blk = blockIdx.x;
        int b   = blk / (NN / 64);
        int n0  = (blk % (NN / 64)) * 64;
        int nl  = t & 63;
        int cq  = t >> 6;
#pragma unroll
        for (int p = 0; p < 16; ++p) {
            int c = cq + p * 4;
            tile[c][nl] = feat[((size_t)b * CC + c) * NN + n0 + nl];   // coalesced
        }
        __syncthreads();
#pragma unroll
        for (int p = 0; p < 16; ++p) {
            int nl2 = cq + p * 4;
            featT[((size_t)b * NN + n0 + nl2) * CC + nl] = tile[nl][nl2]; // coalesced
        }
        return;
    }
    // ---- xyzw pack: grid-stride, scalar reads (no swizzle logic) ----
    int T0     = (blockIdx.x - TRANS_BLOCKS) * 256 + t;
    int stride = XYZW_BLOCKS * 256;
    for (int p = T0; p < BB * NN; p += stride) {
        float x = xyz[(size_t)p * 3 + 0];
        float y = xyz[(size_t)p * 3 + 1];
        float z = xyz[(size_t)p * 3 + 2];
        f32x4 o = {x, y, z, 0.0f};
        xyzw[p] = o;
    }
}

// ---------------------------------------------------------------------------
// Kernel 2: fused ball-query + group, ONE QUERY PER WAVE end-to-end, zero
// block barriers (R8 = measured optimum of the ablation family R4-R13).
// Scan: 128 pts/iter via dwordx4 xyzw loads, ballot-compaction, early exit.
// Group: 4 chunks of 16 channels; wave gathers 64 rows x 16ch (64B per
// 4-lane row group) into a private 64x17 LDS subtile, then NT-stores
// 4x256B segments per instruction. Chunk gathers software-pipelined.
// LDS 18.4KB/block -> 8 blocks/CU -> 32 waves/CU.
// Load-bearing (ablation-verified): NT stores (+12 if plain), 256B store
// segments (+13..35 if narrower), identity work order (+23 if permuted),
// LDS staging (+13 if removed). Bank conflicts: non-critical (R11: 0).
// ---------------------------------------------------------------------------
__global__ __launch_bounds__(256) void fused_qg(const f32x4* __restrict__ xyzw,
                                                const float* __restrict__ nxyz,
                                                const float* __restrict__ featT,
                                                float* __restrict__ out) {
    __shared__ float sub[4][64][17];   // per-wave 64 samples x 16ch (+1 pad)
    __shared__ int   sidx[4][NSAMP];

    int t    = threadIdx.x;
    int wid  = t >> 6;
    int lane = t & 63;
    int wg   = blockIdx.x;
    // XCD swizzle: 4096 blocks (%8==0 bijective); each XCD gets a contiguous
    // half-batch -> featT slice ~4MB = one XCD L2.
    int qblk = (wg & 7) * (BB * SS / 8 / 4) + (wg >> 3);
    int q    = qblk * 4 + wid;
    int b    = q >> 12;
    int s    = q & (SS - 1);

    const f32x4* xp = xyzw + (size_t)b * NN;
    float qx = nxyz[((size_t)b * SS + s) * 3 + 0];
    float qy = nxyz[((size_t)b * SS + s) * 3 + 1];
    float qz = nxyz[((size_t)b * SS + s) * 3 + 2];
    // q2 = (qx*qx + qy*qy) + qz*qz -- numpy f32 sequential, no FMA
    float q2 = __fadd_rn(__fadd_rn(__fmul_rn(qx, qx), __fmul_rn(qy, qy)),
                         __fmul_rn(qz, qz));

    // ---- phase 1: ball query (wave-private, 128 pts/iter, dwordx4 loads) ----
    int cnt = 0;
    f32x4 A  = xp[lane];
    f32x4 Bv = xp[lane + 64];
    for (int base = 0; base < NN; base += 128) {
        f32x4 ca = A, cb = Bv;
        int nb = base + 128;
        if (nb < NN) {            // uniform; prefetch next 128
            A  = xp[nb + lane];
            Bv = xp[nb + 64 + lane];
        }
        // d2 = (q2 + p2) - (qp + qp), numpy-sequential f32 (R4-identical)
        float p2a = __fadd_rn(__fadd_rn(__fmul_rn(ca.x, ca.x), __fmul_rn(ca.y, ca.y)),
                              __fmul_rn(ca.z, ca.z));
        float qpa = __fadd_rn(__fadd_rn(__fmul_rn(qx, ca.x), __fmul_rn(qy, ca.y)),
                              __fmul_rn(qz, ca.z));
        float d2a = __fsub_rn(__fadd_rn(q2, p2a), __fadd_rn(qpa, qpa));
        float p2b = __fadd_rn(__fadd_rn(__fmul_rn(cb.x, cb.x), __fmul_rn(cb.y, cb.y)),
                              __fmul_rn(cb.z, cb.z));
        float qpb = __fadd_rn(__fadd_rn(__fmul_rn(qx, cb.x), __fmul_rn(qy, cb.y)),
                              __fmul_rn(qz, cb.z));
        float d2b = __fsub_rn(__fadd_rn(q2, p2b), __fadd_rn(qpb, qpb));
        bool in0 = d2a < R2;
        bool in1 = d2b < R2;
        unsigned long long m0 = __ballot(in0);
        unsigned long long m1 = __ballot(in1);
        int c0 = __popcll(m0);
        if (in0) {
            int pos = cnt + __popcll(m0 & ((1ull << lane) - 1ull));
            if (pos < NSAMP) sidx[wid][pos] = base + lane;
        }
        if (in1) {
            int pos = cnt + c0 + __popcll(m1 & ((1ull << lane) - 1ull));
            if (pos < NSAMP) sidx[wid][pos] = base + 64 + lane;
        }
        cnt += c0 + __popcll(m1);
        if (cnt >= NSAMP) break;  // uniform
    }
    // wave-synchronous LDS: drain ds ops before reading compaction buffer
    asm volatile("s_waitcnt lgkmcnt(0)" ::: "memory");
    int total = cnt < NSAMP ? cnt : NSAMP;
    int myidx = (total == 0) ? 0 : ((lane < total) ? sidx[wid][lane] : sidx[wid][0]);
    asm volatile("s_waitcnt lgkmcnt(0)" ::: "memory");
    sidx[wid][lane] = myidx;      // normalized (first-index-filled) list
    asm volatile("s_waitcnt lgkmcnt(0)" ::: "memory");

    size_t obase = ((size_t)b * 67) * SS * 64 + (size_t)s * 64;
    size_t chs   = (size_t)SS * 64;

    // ---- grouped_xyz channels 0..2 ----
    {
        const f32x4 P = xp[myidx];
        float gx = __fsub_rn(P.x, qx);
        float gy = __fsub_rn(P.y, qy);
        float gz = __fsub_rn(P.z, qz);
        __builtin_nontemporal_store(gx, out + obase + 0 * chs + lane);
        __builtin_nontemporal_store(gy, out + obase + 1 * chs + lane);
        __builtin_nontemporal_store(gz, out + obase + 2 * chs + lane);
    }

    // ---- phase 2: features, 4 chunks of 16 channels, pipelined ----
    const float* ftb = featT + (size_t)b * NN * CC;
    int r4 = lane >> 2;       // 0..15: row sub-index for gather
    int fc = lane & 3;        // 0..3 : f32x4 within the 16-channel chunk
    int k4 = lane & 15;       // 0..15: sample/4 index for store
    int cs = lane >> 4;       // 0..3 : channel sub-index for store

    int ridx[4];
#pragma unroll
    for (int j = 0; j < 4; ++j) ridx[j] = sidx[wid][j * 16 + r4];
    asm volatile("s_waitcnt lgkmcnt(0)" ::: "memory");

    f32x4 v[4];
#pragma unroll
    for (int j = 0; j < 4; ++j)        // prologue: gather chunk 0
        v[j] = *(const f32x4*)(ftb + (size_t)ridx[j] * CC + fc * 4);

#pragma unroll
    for (int h = 0; h < 4; ++h) {
        f32x4 w[4];
        if (h < 3) {                   // prefetch next chunk's gathers
#pragma unroll
            for (int j = 0; j < 4; ++j)
                w[j] = *(const f32x4*)(ftb + (size_t)ridx[j] * CC + (h + 1) * 16 + fc * 4);
        }
        // stage current chunk into private subtile (2-way banks = free)
#pragma unroll
        for (int j = 0; j < 4; ++j) {
            int row = j * 16 + r4;
            sub[wid][row][fc * 4 + 0] = v[j].x;
            sub[wid][row][fc * 4 + 1] = v[j].y;
            sub[wid][row][fc * 4 + 2] = v[j].z;
            sub[wid][row][fc * 4 + 3] = v[j].w;
        }
        asm volatile("s_waitcnt lgkmcnt(0)" ::: "memory");  // wave-sync LDS
        // store: per instr 4 channels x 256B contiguous segments
#pragma unroll
        for (int j = 0; j < 4; ++j) {
            int cc = j * 4 + cs;              // channel within chunk
            int c  = h * 16 + cc;             // global feature channel
            f32x4 o;
            o.x = sub[wid][k4 * 4 + 0][cc];
            o.y = sub[wid][k4 * 4 + 1][cc];
            o.z = sub[wid][k4 * 4 + 2][cc];
            o.w = sub[wid][k4 * 4 + 3][cc];
            __builtin_nontemporal_store(o,
                (f32x4*)(out + obase + (size_t)(3 + c) * chs + k4 * 4));
        }
        asm volatile("s_waitcnt lgkmcnt(0)" ::: "memory");  // reads done before overwrite
#pragma unroll
        for (int j = 0; j < 4; ++j) v[j] = w[j];
    }
}

// ---------------------------------------------------------------------------
// Fallback (ws too small): fused one-wave-per-query, direct (C,N) gather.
// ---------------------------------------------------------------------------
__global__ __launch_bounds__(64) void qg_fallback(const float* __restrict__ xyz,
                                                  const float* __restrict__ nxyz,
                                                  const float* __restrict__ feat,
                                                  float* __restrict__ out) {
    __shared__ int sidx[NSAMP];
    int q = blockIdx.x;
    int b = q >> 12, s = q & (SS - 1);
    int lane = threadIdx.x;
    const float* xb = xyz + (size_t)b * NN * 3;
    float qx = nxyz[((size_t)b * SS + s) * 3 + 0];
    float qy = nxyz[((size_t)b * SS + s) * 3 + 1];
    float qz = nxyz[((size_t)b * SS + s) * 3 + 2];
    float q2 = __fadd_rn(__fadd_rn(__fmul_rn(qx, qx), __fmul_rn(qy, qy)),
                         __fmul_rn(qz, qz));
    int cnt = 0;
    for (int base = 0; base < NN; base += 64) {
        float cx = xb[(size_t)(base + lane) * 3 + 0];
        float cy = xb[(size_t)(base + lane) * 3 + 1];
        float cz = xb[(size_t)(base + lane) * 3 + 2];
        float p2 = __fadd_rn(__fadd_rn(__fmul_rn(cx, cx), __fmul_rn(cy, cy)),
                             __fmul_rn(cz, cz));
        float qp = __fadd_rn(__fadd_rn(__fmul_rn(qx, cx), __fmul_rn(qy, cy)),
                             __fmul_rn(qz, cz));
        float d2 = __fsub_rn(__fadd_rn(q2, p2), __fadd_rn(qp, qp));
        bool in = d2 < R2;
        unsigned long long m = __ballot(in);
        if (in) {
            int pos = cnt + __popcll(m & ((1ull << lane) - 1ull));
            if (pos < NSAMP) sidx[pos] = base + lane;
        }
        cnt += __popcll(m);
        if (cnt >= NSAMP) break;
    }
    __syncthreads();
    int total = cnt < NSAMP ? cnt : NSAMP;
    int myidx = (total == 0) ? 0 : ((lane < total) ? sidx[lane] : sidx[0]);
    size_t obase = ((size_t)b * 67) * SS * 64 + (size_t)s * 64;
    size_t chs   = (size_t)SS * 64;
    out[obase + 0 * chs + lane] = __fsub_rn(xb[(size_t)myidx * 3 + 0], qx);
    out[obase + 1 * chs + lane] = __fsub_rn(xb[(size_t)myidx * 3 + 1], qy);
    out[obase + 2 * chs + lane] = __fsub_rn(xb[(size_t)myidx * 3 + 2], qz);
    const float* fb = feat + (size_t)b * CC * NN;
#pragma unroll 4
    for (int c = 0; c < CC; ++c)
        out[obase + (size_t)(3 + c) * chs + lane] = fb[(size_t)c * NN + myidx];
}

// ---------------------------------------------------------------------------
extern "C" void kernel_launch(void* const* d_in, const int* in_sizes, int n_in,
                              void* d_out, int out_size, void* d_ws, size_t ws_size,
                              hipStream_t stream) {
    const float* xyz  = (const float*)d_in[0];   // (B,N,3)
    const float* nxyz = (const float*)d_in[1];   // (B,S,3)
    const float* feat = (const float*)d_in[2];   // (B,C,N)
    float* out = (float*)d_out;                  // (B,67,S,64)

    size_t needT = (size_t)BB * NN * CC * sizeof(float);        // 16 MB
    size_t needW = (size_t)BB * NN * 4 * sizeof(float);         //  1 MB
    if (ws_size >= needT + needW) {
        float* featT = (float*)d_ws;
        f32x4* xyzw  = (f32x4*)((char*)d_ws + needT);
        prep_kernel<<<TRANS_BLOCKS + XYZW_BLOCKS, 256, 0, stream>>>(xyz, feat,
                                                                    featT, xyzw);
        fused_qg<<<BB * SS / 4, 256, 0, stream>>>(xyzw, nxyz, featT, out);
    } else {
        qg_fallback<<<BB * SS, 64, 0, stream>>>(xyz, nxyz, feat, out);
    }
}